// Round 1
// baseline (1301.599 us; speedup 1.0000x reference)
//
#include <hip/hip_runtime.h>

typedef __bf16 bf16_t;
typedef __bf16 bf16x8 __attribute__((ext_vector_type(8)));
typedef __bf16 bf16x4 __attribute__((ext_vector_type(4)));
typedef float f32x4 __attribute__((ext_vector_type(4)));

#define S_LEN 2048
#define NH 32
#define NKV 8
#define HD 128
#define B_SZ 2
#define HID 4096
#define INFF __builtin_inff()

// ---------------- fp32 -> bf16 convert ----------------
__global__ __launch_bounds__(256) void f2b_kernel(const float4* __restrict__ in,
                                                  bf16x4* __restrict__ out, int n4) {
    int i = blockIdx.x * blockDim.x + threadIdx.x;
    if (i >= n4) return;
    float4 v = in[i];
    bf16x4 o = {(bf16_t)v.x, (bf16_t)v.y, (bf16_t)v.z, (bf16_t)v.w};
    out[i] = o;
}

// ---------------- GEMM: C[M,N] = A[M,K] @ W[N,K]^T (bf16 in, bf16/f32 out) ----------------
#define TILE 128
#define KSTEP 32
#define LDSP 40  // padded LDS row (bf16 elems); multiple of 8 for 16B-aligned b128 reads

template<bool F32OUT>
__global__ __launch_bounds__(256) void gemm_bt(const bf16_t* __restrict__ A,
                                               const bf16_t* __restrict__ W,
                                               void* __restrict__ Cv,
                                               int M, int N, int K) {
    __shared__ bf16_t lds_a[TILE * LDSP];
    __shared__ bf16_t lds_b[TILE * LDSP];
    const int tid = threadIdx.x;
    const int lane = tid & 63;
    const int w = tid >> 6;
    const int wr = w >> 1, wc = w & 1;
    const int m0 = blockIdx.y * TILE;
    const int n0 = blockIdx.x * TILE;
    const int l15 = lane & 15, lg = lane >> 4;
    f32x4 acc[4][4] = {};

    for (int kk = 0; kk < K; kk += KSTEP) {
        __syncthreads();
        // stage 128x32 A-tile and 128x32 W-tile (bf16x8 chunks, 2 per thread each)
        for (int it = 0; it < 2; ++it) {
            int idx = tid + it * 256;          // 0..511
            int row = idx >> 2, c = idx & 3;   // row 0..127, chunk 0..3
            *(bf16x8*)&lds_a[row * LDSP + c * 8] =
                *(const bf16x8*)&A[(size_t)(m0 + row) * K + kk + c * 8];
            *(bf16x8*)&lds_b[row * LDSP + c * 8] =
                *(const bf16x8*)&W[(size_t)(n0 + row) * K + kk + c * 8];
        }
        __syncthreads();
        bf16x8 af[4], bfr[4];
        for (int i = 0; i < 4; ++i)
            af[i] = *(bf16x8*)&lds_a[(wr * 64 + i * 16 + l15) * LDSP + lg * 8];
        for (int j = 0; j < 4; ++j)
            bfr[j] = *(bf16x8*)&lds_b[(wc * 64 + j * 16 + l15) * LDSP + lg * 8];
        for (int i = 0; i < 4; ++i)
            for (int j = 0; j < 4; ++j)
                acc[i][j] = __builtin_amdgcn_mfma_f32_16x16x32_bf16(af[i], bfr[j], acc[i][j], 0, 0, 0);
    }

    for (int i = 0; i < 4; ++i)
        for (int j = 0; j < 4; ++j)
            for (int r = 0; r < 4; ++r) {
                int m = m0 + wr * 64 + i * 16 + lg * 4 + r;
                int n = n0 + wc * 64 + j * 16 + l15;
                float v = acc[i][j][r];
                if (F32OUT) ((float*)Cv)[(size_t)m * N + n] = v;
                else        ((bf16_t*)Cv)[(size_t)m * N + n] = (bf16_t)v;
            }
}

// ---------------- RoPE (in-place on Q and K, bf16) ----------------
__global__ __launch_bounds__(256) void rope_kernel(bf16_t* __restrict__ Qb,
                                                   bf16_t* __restrict__ Kb,
                                                   const float* __restrict__ cosb,
                                                   const float* __restrict__ sinb) {
    int tid = blockIdx.x * blockDim.x + threadIdx.x;  // exactly B*S*40*64 threads
    int d = tid & 63;
    int h40 = (tid >> 6) % (NH + NKV);
    int bs = tid / (64 * (NH + NKV));
    bf16_t* buf;
    int heads, h;
    if (h40 < NH) { buf = Qb; heads = NH; h = h40; }
    else          { buf = Kb; heads = NKV; h = h40 - NH; }
    size_t base = ((size_t)bs * heads + h) * HD;
    float x1 = (float)buf[base + d];
    float x2 = (float)buf[base + d + 64];
    float c1 = cosb[(size_t)bs * HD + d];
    float s1 = sinb[(size_t)bs * HD + d];
    float c2 = cosb[(size_t)bs * HD + d + 64];
    float s2 = sinb[(size_t)bs * HD + d + 64];
    buf[base + d]      = (bf16_t)(x1 * c1 - x2 * s1);
    buf[base + d + 64] = (bf16_t)(x2 * c2 + x1 * s2);
}

// ---------------- Flash attention (causal, GQA) ----------------
#define QB 16
#define KB 32

__global__ __launch_bounds__(64) void attn_fwd(const bf16_t* __restrict__ Q,
                                               const bf16_t* __restrict__ Kk,
                                               const bf16_t* __restrict__ Vv,
                                               bf16_t* __restrict__ O) {
    __shared__ bf16_t Vt[HD * LDSP];   // V^T tile: [d][k], k-row padded to 40
    __shared__ bf16_t Pl[QB * LDSP];   // P tile:  [q][k]
    const int lane = threadIdx.x;
    const int l15 = lane & 15, lg = lane >> 4;
    const int qt = blockIdx.x, h = blockIdx.y, b = blockIdx.z;
    const int kvh = h >> 2;            // NH/NKV = 4
    const int q0 = qt * QB;
    const float scale = 0.08838834764831845f;  // 1/sqrt(128)

    // Q fragments: A-operand, m = l15 (q-row), k = c*32 + lg*8 + i (d)
    bf16x8 qf[4];
    const size_t qbase = ((size_t)(b * S_LEN + q0 + l15) * NH + h) * HD;
    for (int c = 0; c < 4; ++c)
        qf[c] = *(const bf16x8*)&Q[qbase + c * 32 + lg * 8];

    f32x4 acc_o[8] = {};
    float mrow[4], lrow[4];
    for (int r = 0; r < 4; ++r) { mrow[r] = -INFF; lrow[r] = 0.f; }

    const int nsteps = (q0 + QB + KB - 1) / KB;
    for (int st = 0; st < nsteps; ++st) {
        const int k0 = st * KB;
        __syncthreads();
        // stage V^T: rows k0..k0+31, all 128 d; Vt[d][kr]
        for (int it = 0; it < 8; ++it) {
            int idx = it * 64 + lane;       // 0..511
            int kr = idx & 31, c8 = idx >> 5;  // kr 0..31, c8 0..15
            int srow = k0 + kr; if (srow > S_LEN - 1) srow = S_LEN - 1;
            bf16x8 v = *(const bf16x8*)&Vv[((size_t)(b * S_LEN + srow) * NKV + kvh) * HD + c8 * 8];
            for (int j = 0; j < 8; ++j)
                Vt[(c8 * 8 + j) * LDSP + kr] = v[j];
        }
        // QK^T: two 16-col tiles
        f32x4 s0 = {}, s1 = {};
        int kr0 = k0 + l15;       if (kr0 > S_LEN - 1) kr0 = S_LEN - 1;
        int kr1 = k0 + 16 + l15;  if (kr1 > S_LEN - 1) kr1 = S_LEN - 1;
        size_t kb0 = ((size_t)(b * S_LEN + kr0) * NKV + kvh) * HD;
        size_t kb1 = ((size_t)(b * S_LEN + kr1) * NKV + kvh) * HD;
        for (int c = 0; c < 4; ++c) {
            bf16x8 kf0 = *(const bf16x8*)&Kk[kb0 + c * 32 + lg * 8];
            bf16x8 kf1 = *(const bf16x8*)&Kk[kb1 + c * 32 + lg * 8];
            s0 = __builtin_amdgcn_mfma_f32_16x16x32_bf16(qf[c], kf0, s0, 0, 0, 0);
            s1 = __builtin_amdgcn_mfma_f32_16x16x32_bf16(qf[c], kf1, s1, 0, 0, 0);
        }
        // online softmax; rows of this thread: q0 + lg*4 + r
        float p0[4], p1[4], scf[4];
        for (int r = 0; r < 4; ++r) {
            int qg = q0 + lg * 4 + r;
            float v0 = (k0 + l15      <= qg) ? s0[r] * scale : -INFF;
            float v1 = (k0 + 16 + l15 <= qg) ? s1[r] * scale : -INFF;
            float tm = fmaxf(v0, v1);
            for (int off = 1; off < 16; off <<= 1)
                tm = fmaxf(tm, __shfl_xor(tm, off));
            float mn = fmaxf(mrow[r], tm);
            float sc = __expf(mrow[r] - mn);
            float e0 = __expf(v0 - mn);
            float e1 = __expf(v1 - mn);
            float rs = e0 + e1;
            for (int off = 1; off < 16; off <<= 1)
                rs += __shfl_xor(rs, off);
            mrow[r] = mn;
            lrow[r] = lrow[r] * sc + rs;
            scf[r] = sc; p0[r] = e0; p1[r] = e1;
        }
        for (int nt = 0; nt < 8; ++nt)
            for (int r = 0; r < 4; ++r) acc_o[nt][r] *= scf[r];
        // write P (C/D layout -> LDS rows)
        for (int r = 0; r < 4; ++r) {
            int prow = lg * 4 + r;
            Pl[prow * LDSP + l15]      = (bf16_t)p0[r];
            Pl[prow * LDSP + 16 + l15] = (bf16_t)p1[r];
        }
        __syncthreads();
        // PV: A = P (m=l15 q-row, k=lg*8), B = V^T rows
        bf16x8 pf = *(const bf16x8*)&Pl[l15 * LDSP + lg * 8];
        for (int nt = 0; nt < 8; ++nt) {
            bf16x8 vf = *(const bf16x8*)&Vt[(nt * 16 + l15) * LDSP + lg * 8];
            acc_o[nt] = __builtin_amdgcn_mfma_f32_16x16x32_bf16(pf, vf, acc_o[nt], 0, 0, 0);
        }
    }
    // epilogue: O[b,s,h,d] = acc/l
    for (int nt = 0; nt < 8; ++nt)
        for (int r = 0; r < 4; ++r) {
            int q = q0 + lg * 4 + r;
            int d = nt * 16 + l15;
            float v = acc_o[nt][r] / lrow[r];
            O[((size_t)(b * S_LEN + q) * NH + h) * HD + d] = (bf16_t)v;
        }
}

// ---------------- launch ----------------
extern "C" void kernel_launch(void* const* d_in, const int* in_sizes, int n_in,
                              void* d_out, int out_size, void* d_ws, size_t ws_size,
                              hipStream_t stream) {
    const float* hs   = (const float*)d_in[0];
    const float* cosb = (const float*)d_in[1];
    const float* sinb = (const float*)d_in[2];
    const float* wq   = (const float*)d_in[3];
    const float* wk   = (const float*)d_in[4];
    const float* wv   = (const float*)d_in[5];
    const float* wo   = (const float*)d_in[6];
    float* out = (float*)d_out;

    const size_t NHS = (size_t)B_SZ * S_LEN * HID;      // 16777216
    const size_t NKW = (size_t)NKV * HD * HID;          // 4194304
    size_t need = (NHS * 5 + NKW * 4) * sizeof(bf16_t); // ~201 MB
    if (ws_size < need) return;

    bf16_t* p = (bf16_t*)d_ws;
    bf16_t* hsb = p; p += NHS;
    bf16_t* wqb = p; p += NHS;
    bf16_t* wkb = p; p += NKW;
    bf16_t* wvb = p; p += NKW;
    bf16_t* wob = p; p += NHS;
    bf16_t* Qb  = p; p += NHS;
    bf16_t* Kb  = p; p += NKW;
    bf16_t* Vb  = p; p += NKW;
    bf16_t* Ab  = p; p += NHS;

    auto cvt = [&](const float* src, bf16_t* dst, size_t n) {
        int n4 = (int)(n / 4);
        f2b_kernel<<<(n4 + 255) / 256, 256, 0, stream>>>((const float4*)src, (bf16x4*)dst, n4);
    };
    cvt(hs, hsb, NHS);
    cvt(wq, wqb, NHS);
    cvt(wk, wkb, NKW);
    cvt(wv, wvb, NKW);
    cvt(wo, wob, NHS);

    const int M = B_SZ * S_LEN;  // 4096
    gemm_bt<false><<<dim3(HID / TILE, M / TILE), 256, 0, stream>>>(hsb, wqb, Qb, M, HID, HID);
    gemm_bt<false><<<dim3(NKV * HD / TILE, M / TILE), 256, 0, stream>>>(hsb, wkb, Kb, M, NKV * HD, HID);
    gemm_bt<false><<<dim3(NKV * HD / TILE, M / TILE), 256, 0, stream>>>(hsb, wvb, Vb, M, NKV * HD, HID);

    int rope_threads = B_SZ * S_LEN * (NH + NKV) * 64;  // 10485760
    rope_kernel<<<rope_threads / 256, 256, 0, stream>>>(Qb, Kb, cosb, sinb);

    attn_fwd<<<dim3(S_LEN / QB, NH, B_SZ), 64, 0, stream>>>(Qb, Kb, Vb, Ab);

    gemm_bt<true><<<dim3(HID / TILE, M / TILE), 256, 0, stream>>>(Ab, wob, out, M, HID, HID);
}

// Round 2
// 871.247 us; speedup vs baseline: 1.4939x; 1.4939x over previous
//
#include <hip/hip_runtime.h>
#include <stdint.h>

typedef __bf16 bf16_t;
typedef __bf16 bf16x8 __attribute__((ext_vector_type(8)));
typedef __bf16 bf16x4 __attribute__((ext_vector_type(4)));
typedef float f32x4 __attribute__((ext_vector_type(4)));

#define S_LEN 2048
#define NH 32
#define NKV 8
#define HD 128
#define B_SZ 2
#define HID 4096
#define QKV_N 6144
#define INFF __builtin_inff()

// global -> LDS direct copy, 16B per lane. LDS dest must be linear (base+lane*16).
__device__ __forceinline__ void gload_lds16(const void* g, void* l) {
    __builtin_amdgcn_global_load_lds(
        (const __attribute__((address_space(1))) void*)(uintptr_t)g,
        (__attribute__((address_space(3))) void*)(uint32_t)(uintptr_t)l,
        16, 0, 0);
}

// ---------------- fp32 -> bf16 convert ----------------
__global__ __launch_bounds__(256) void f2b_kernel(const float4* __restrict__ in,
                                                  bf16x4* __restrict__ out, int n4) {
    int i = blockIdx.x * blockDim.x + threadIdx.x;
    if (i >= n4) return;
    float4 v = in[i];
    bf16x4 o = {(bf16_t)v.x, (bf16_t)v.y, (bf16_t)v.z, (bf16_t)v.w};
    out[i] = o;
}

// ---------------- GEMM: C[M,N] = A[M,K] @ W[N,K]^T (m97 structure) ----------------
template<bool F32OUT>
__global__ __launch_bounds__(256) void gemm_bt(const bf16_t* __restrict__ A,
                                               const bf16_t* __restrict__ W,
                                               void* __restrict__ Cv,
                                               int M, int N, int K) {
    __shared__ __align__(16) bf16_t lds_a[128 * 32];
    __shared__ __align__(16) bf16_t lds_b[128 * 32];
    const int tid = threadIdx.x;
    const int lane = tid & 63;
    const int w = tid >> 6;
    const int wr = w >> 1, wc = w & 1;
    const int m0 = blockIdx.y * 128;
    const int n0 = blockIdx.x * 128;
    const int l15 = lane & 15, lg = lane >> 4;

    // staging: 512 chunks of 16B per tile; chunk q -> row=q>>2, ch=q&3,
    // source column pre-swizzled with key=(row>>1)&3 (both-sides swizzle)
    const int q1 = w * 128 + lane, q2 = q1 + 64;
    const int r1 = q1 >> 2, c1 = q1 & 3;
    const int r2 = q2 >> 2, c2 = q2 & 3;
    const bf16_t* sA1 = A + (size_t)(m0 + r1) * K + ((c1 ^ ((r1 >> 1) & 3)) * 8);
    const bf16_t* sA2 = A + (size_t)(m0 + r2) * K + ((c2 ^ ((r2 >> 1) & 3)) * 8);
    const bf16_t* sB1 = W + (size_t)(n0 + r1) * K + ((c1 ^ ((r1 >> 1) & 3)) * 8);
    const bf16_t* sB2 = W + (size_t)(n0 + r2) * K + ((c2 ^ ((r2 >> 1) & 3)) * 8);
    bf16_t* dA1 = &lds_a[q1 * 8]; bf16_t* dA2 = &lds_a[q2 * 8];
    bf16_t* dB1 = &lds_b[q1 * 8]; bf16_t* dB2 = &lds_b[q2 * 8];

    int offA[4], offB[4];
    for (int i = 0; i < 4; ++i) {
        int rowa = wr * 64 + i * 16 + l15;
        offA[i] = rowa * 32 + ((lg ^ ((rowa >> 1) & 3)) * 8);
        int rowb = wc * 64 + i * 16 + l15;
        offB[i] = rowb * 32 + ((lg ^ ((rowb >> 1) & 3)) * 8);
    }

    f32x4 acc[4][4] = {};
    for (int kk = 0; kk < K; kk += 32) {
        __syncthreads();
        gload_lds16(sA1, dA1); gload_lds16(sA2, dA2);
        gload_lds16(sB1, dB1); gload_lds16(sB2, dB2);
        sA1 += 32; sA2 += 32; sB1 += 32; sB2 += 32;
        __syncthreads();
        bf16x8 af[4], bfr[4];
        for (int i = 0; i < 4; ++i) af[i] = *(bf16x8*)&lds_a[offA[i]];
        for (int j = 0; j < 4; ++j) bfr[j] = *(bf16x8*)&lds_b[offB[j]];
        for (int i = 0; i < 4; ++i)
            for (int j = 0; j < 4; ++j)
                acc[i][j] = __builtin_amdgcn_mfma_f32_16x16x32_bf16(af[i], bfr[j], acc[i][j], 0, 0, 0);
    }

    for (int i = 0; i < 4; ++i)
        for (int j = 0; j < 4; ++j)
            for (int r = 0; r < 4; ++r) {
                int m = m0 + wr * 64 + i * 16 + lg * 4 + r;
                int n = n0 + wc * 64 + j * 16 + l15;
                float v = acc[i][j][r];
                if (F32OUT) ((float*)Cv)[(size_t)m * N + n] = v;
                else        ((bf16_t*)Cv)[(size_t)m * N + n] = (bf16_t)v;
            }
}

// ---------------- RoPE (in-place on fused QKV buffer) ----------------
__global__ __launch_bounds__(256) void rope_kernel(bf16_t* __restrict__ QKV,
                                                   const float* __restrict__ cosb,
                                                   const float* __restrict__ sinb) {
    int tid = blockIdx.x * blockDim.x + threadIdx.x;  // B*S*40*64 threads
    int d = tid & 63;
    int h40 = (tid >> 6) % (NH + NKV);
    int bs = tid / (64 * (NH + NKV));
    int col = (h40 < NH) ? h40 * HD : HID + (h40 - NH) * HD;
    bf16_t* rowp = QKV + (size_t)bs * QKV_N + col;
    float x1 = (float)rowp[d];
    float x2 = (float)rowp[d + 64];
    float c1 = cosb[(size_t)bs * HD + d];
    float s1 = sinb[(size_t)bs * HD + d];
    float c2 = cosb[(size_t)bs * HD + d + 64];
    float s2 = sinb[(size_t)bs * HD + d + 64];
    rowp[d]      = (bf16_t)(x1 * c1 - x2 * s1);
    rowp[d + 64] = (bf16_t)(x2 * c2 + x1 * s2);
}

// ---------------- Flash attention (causal, GQA): QB=64 (4 waves), KB=64 ----------------
__global__ __launch_bounds__(256) void attn_fwd(const bf16_t* __restrict__ QKV,
                                                bf16_t* __restrict__ O) {
    __shared__ __align__(16) bf16_t Kl[64 * 128];     // swizzled chunks, linear rows (16KB)
    __shared__ __align__(16) bf16_t Vt[128 * 72];     // V^T [d][k], pitch 72 (18KB)
    __shared__ __align__(16) bf16_t Pl[4][16 * 72];   // per-wave P tile (9KB)
    const int tid = threadIdx.x;
    const int lane = tid & 63;
    const int w = tid >> 6;
    const int l15 = lane & 15, lg = lane >> 4;
    const int qt = blockIdx.x, h = blockIdx.y, b = blockIdx.z;
    const int kvh = h >> 2;
    const int q0 = qt * 64;
    const float scale = 0.08838834764831845f;  // 1/sqrt(128)

    // Q fragments: 16 rows per wave, A-operand (m=l15, k=c*32+lg*8)
    bf16x8 qf[4];
    {
        const bf16_t* qp = QKV + (size_t)(b * S_LEN + q0 + w * 16 + l15) * QKV_N + h * HD;
        for (int c = 0; c < 4; ++c)
            qf[c] = *(const bf16x8*)&qp[c * 32 + lg * 8];
    }

    // K staging: 1024 chunks; LDS dest linear, global source chunk ^= (row&7)
    int koff[4]; bf16_t* kdst[4];
    for (int jj = 0; jj < 4; ++jj) {
        int q = jj * 256 + tid;
        int row = q >> 4, ch = q & 15;
        koff[jj] = row * QKV_N + ((ch ^ (row & 7)) * 8);
        kdst[jj] = &Kl[q * 8];
    }
    // V transpose staging: thread owns 4(k) x 8(d) block
    const int k0v = (tid & 15) * 4;
    const int d0 = (tid >> 4) * 8;

    const bf16_t* Kbase = QKV + (size_t)(b * S_LEN) * QKV_N + HID + kvh * HD;
    const bf16_t* Vbase = QKV + (size_t)(b * S_LEN) * QKV_N + HID + NKV * HD + kvh * HD;

    f32x4 acc_o[8] = {};
    float mrow[4], lrow[4];
    for (int r = 0; r < 4; ++r) { mrow[r] = -INFF; lrow[r] = 0.f; }

    const int nsteps = qt + 1;
    for (int st = 0; st < nsteps; ++st) {
        const int k0 = st * 64;
        // issue V global loads before the barrier (latency hides under barrier+K issue)
        bf16x8 v0 = *(const bf16x8*)&Vbase[(size_t)(k0v + 0) * QKV_N + d0];
        bf16x8 v1 = *(const bf16x8*)&Vbase[(size_t)(k0v + 1) * QKV_N + d0];
        bf16x8 v2 = *(const bf16x8*)&Vbase[(size_t)(k0v + 2) * QKV_N + d0];
        bf16x8 v3 = *(const bf16x8*)&Vbase[(size_t)(k0v + 3) * QKV_N + d0];
        __syncthreads();   // prev step's LDS reads complete
        for (int jj = 0; jj < 4; ++jj)
            gload_lds16(Kbase + koff[jj], kdst[jj]);
        for (int j = 0; j < 8; ++j) {
            bf16x4 c = {v0[j], v1[j], v2[j], v3[j]};
            *(bf16x4*)&Vt[(d0 + j) * 72 + k0v] = c;
        }
        __syncthreads();   // K (vmcnt drained by compiler) + Vt ready

        // QK^T: S[16q][64k] per wave
        f32x4 s[4] = {};
        for (int nt = 0; nt < 4; ++nt) {
            int row = nt * 16 + l15;
            int rb = row * 128, key = row & 7;
            for (int c = 0; c < 4; ++c) {
                bf16x8 kf = *(const bf16x8*)&Kl[rb + (((c * 4 + lg) ^ key) * 8)];
                s[nt] = __builtin_amdgcn_mfma_f32_16x16x32_bf16(qf[c], kf, s[nt], 0, 0, 0);
            }
        }
        // online softmax (rows r: q = q0+w*16+lg*4+r)
        const bool needmask = (k0 + 63) > (q0 + w * 16);
        float p[4][4], scf[4];
        for (int r = 0; r < 4; ++r) {
            const int qrow = q0 + w * 16 + lg * 4 + r;
            float tm = -INFF;
            for (int nt = 0; nt < 4; ++nt) {
                float v = s[nt][r] * scale;
                if (needmask && (k0 + nt * 16 + l15) > qrow) v = -INFF;
                p[nt][r] = v;
                tm = fmaxf(tm, v);
            }
            tm = fmaxf(tm, __shfl_xor(tm, 1));
            tm = fmaxf(tm, __shfl_xor(tm, 2));
            tm = fmaxf(tm, __shfl_xor(tm, 4));
            tm = fmaxf(tm, __shfl_xor(tm, 8));
            float mn = fmaxf(mrow[r], tm);
            float sc = __expf(mrow[r] - mn);
            float rs = 0.f;
            for (int nt = 0; nt < 4; ++nt) {
                float e = __expf(p[nt][r] - mn);
                p[nt][r] = e; rs += e;
            }
            rs += __shfl_xor(rs, 1);
            rs += __shfl_xor(rs, 2);
            rs += __shfl_xor(rs, 4);
            rs += __shfl_xor(rs, 8);
            mrow[r] = mn;
            lrow[r] = lrow[r] * sc + rs;
            scf[r] = sc;
        }
        for (int nt = 0; nt < 8; ++nt)
            for (int r = 0; r < 4; ++r) acc_o[nt][r] *= scf[r];
        // P -> LDS (per-wave buffer, no cross-wave barrier needed)
        for (int nt = 0; nt < 4; ++nt)
            for (int r = 0; r < 4; ++r)
                Pl[w][(lg * 4 + r) * 72 + nt * 16 + l15] = (bf16_t)p[nt][r];
        // PV: O += P @ V  (A = P[m=q][k=kv], B = Vt[n=d][k=kv])
        for (int kc = 0; kc < 2; ++kc) {
            bf16x8 pf = *(const bf16x8*)&Pl[w][l15 * 72 + kc * 32 + lg * 8];
            for (int nt = 0; nt < 8; ++nt) {
                bf16x8 vf = *(const bf16x8*)&Vt[(nt * 16 + l15) * 72 + kc * 32 + lg * 8];
                acc_o[nt] = __builtin_amdgcn_mfma_f32_16x16x32_bf16(pf, vf, acc_o[nt], 0, 0, 0);
            }
        }
        Kbase += (size_t)64 * QKV_N;
        Vbase += (size_t)64 * QKV_N;
    }
    // epilogue
    for (int nt = 0; nt < 8; ++nt)
        for (int r = 0; r < 4; ++r) {
            int q = q0 + w * 16 + lg * 4 + r;
            int d = nt * 16 + l15;
            O[((size_t)(b * S_LEN + q)) * (NH * HD) + h * HD + d] = (bf16_t)(acc_o[nt][r] / lrow[r]);
        }
}

// ---------------- launch ----------------
extern "C" void kernel_launch(void* const* d_in, const int* in_sizes, int n_in,
                              void* d_out, int out_size, void* d_ws, size_t ws_size,
                              hipStream_t stream) {
    const float* hs   = (const float*)d_in[0];
    const float* cosb = (const float*)d_in[1];
    const float* sinb = (const float*)d_in[2];
    const float* wq   = (const float*)d_in[3];
    const float* wk   = (const float*)d_in[4];
    const float* wv   = (const float*)d_in[5];
    const float* wo   = (const float*)d_in[6];
    float* out = (float*)d_out;

    const size_t NHS = (size_t)B_SZ * S_LEN * HID;          // 16777216
    const size_t NQKVW = (size_t)QKV_N * HID;               // 25165824
    size_t need = (NHS * 3 + NQKVW * 2) * sizeof(bf16_t);   // ~201 MB
    if (ws_size < need) return;

    bf16_t* p = (bf16_t*)d_ws;
    bf16_t* hsb  = p; p += NHS;     // [4096][4096]
    bf16_t* wqkv = p; p += NQKVW;   // [6144][4096] = wq;wk;wv
    bf16_t* wob  = p; p += NHS;     // [4096][4096]
    bf16_t* QKVb = p; p += NQKVW;   // [4096][6144]
    bf16_t* Ab   = p; p += NHS;     // [4096][4096]

    auto cvt = [&](const float* src, bf16_t* dst, size_t n) {
        int n4 = (int)(n / 4);
        f2b_kernel<<<(n4 + 255) / 256, 256, 0, stream>>>((const float4*)src, (bf16x4*)dst, n4);
    };
    cvt(hs, hsb, NHS);
    cvt(wq, wqkv, NHS);                                      // rows 0..4095
    cvt(wk, wqkv + (size_t)HID * HID, (size_t)NKV * HD * HID);          // rows 4096..5119
    cvt(wv, wqkv + (size_t)(HID + NKV * HD) * HID, (size_t)NKV * HD * HID); // rows 5120..6143
    cvt(wo, wob, NHS);

    const int M = B_SZ * S_LEN;  // 4096
    gemm_bt<false><<<dim3(QKV_N / 128, M / 128), 256, 0, stream>>>(hsb, wqkv, QKVb, M, QKV_N, HID);

    int rope_threads = B_SZ * S_LEN * (NH + NKV) * 64;
    rope_kernel<<<rope_threads / 256, 256, 0, stream>>>(QKVb, cosb, sinb);

    attn_fwd<<<dim3(S_LEN / 64, NH, B_SZ), 256, 0, stream>>>(QKVb, Ab);

    gemm_bt<true><<<dim3(HID / 128, M / 128), 256, 0, stream>>>(Ab, wob, out, M, HID, HID);
}

// Round 3
// 701.674 us; speedup vs baseline: 1.8550x; 1.2417x over previous
//
#include <hip/hip_runtime.h>
#include <stdint.h>

typedef __bf16 bf16_t;
typedef __bf16 bf16x8 __attribute__((ext_vector_type(8)));
typedef __bf16 bf16x4 __attribute__((ext_vector_type(4)));
typedef float f32x4 __attribute__((ext_vector_type(4)));

#define S_LEN 2048
#define NH 32
#define NKV 8
#define HD 128
#define B_SZ 2
#define HID 4096
#define QKV_N 6144
#define INFF __builtin_inff()

// global -> LDS direct copy, 16B per lane. LDS dest must be linear (base+lane*16).
__device__ __forceinline__ void gload_lds16(const void* g, void* l) {
    __builtin_amdgcn_global_load_lds(
        (const __attribute__((address_space(1))) void*)(uintptr_t)g,
        (__attribute__((address_space(3))) void*)(uint32_t)(uintptr_t)l,
        16, 0, 0);
}

// ---------------- fp32 -> bf16 convert ----------------
__global__ __launch_bounds__(256) void f2b_kernel(const float4* __restrict__ in,
                                                  bf16x4* __restrict__ out, int n4) {
    int i = blockIdx.x * blockDim.x + threadIdx.x;
    if (i >= n4) return;
    float4 v = in[i];
    bf16x4 o = {(bf16_t)v.x, (bf16_t)v.y, (bf16_t)v.z, (bf16_t)v.w};
    out[i] = o;
}

// ---------------- GEMM: C[M,N] = A[M,K] @ W[N,K]^T (m97 structure) ----------------
template<bool F32OUT>
__global__ __launch_bounds__(256) void gemm_bt(const bf16_t* __restrict__ A,
                                               const bf16_t* __restrict__ W,
                                               void* __restrict__ Cv,
                                               int M, int N, int K) {
    __shared__ __align__(16) bf16_t lds_a[128 * 32];
    __shared__ __align__(16) bf16_t lds_b[128 * 32];
    const int tid = threadIdx.x;
    const int lane = tid & 63;
    const int w = tid >> 6;
    const int wr = w >> 1, wc = w & 1;
    const int m0 = blockIdx.y * 128;
    const int n0 = blockIdx.x * 128;
    const int l15 = lane & 15, lg = lane >> 4;

    const int q1 = w * 128 + lane, q2 = q1 + 64;
    const int r1 = q1 >> 2, c1 = q1 & 3;
    const int r2 = q2 >> 2, c2 = q2 & 3;
    const bf16_t* sA1 = A + (size_t)(m0 + r1) * K + ((c1 ^ ((r1 >> 1) & 3)) * 8);
    const bf16_t* sA2 = A + (size_t)(m0 + r2) * K + ((c2 ^ ((r2 >> 1) & 3)) * 8);
    const bf16_t* sB1 = W + (size_t)(n0 + r1) * K + ((c1 ^ ((r1 >> 1) & 3)) * 8);
    const bf16_t* sB2 = W + (size_t)(n0 + r2) * K + ((c2 ^ ((r2 >> 1) & 3)) * 8);
    bf16_t* dA1 = &lds_a[q1 * 8]; bf16_t* dA2 = &lds_a[q2 * 8];
    bf16_t* dB1 = &lds_b[q1 * 8]; bf16_t* dB2 = &lds_b[q2 * 8];

    int offA[4], offB[4];
    for (int i = 0; i < 4; ++i) {
        int rowa = wr * 64 + i * 16 + l15;
        offA[i] = rowa * 32 + ((lg ^ ((rowa >> 1) & 3)) * 8);
        int rowb = wc * 64 + i * 16 + l15;
        offB[i] = rowb * 32 + ((lg ^ ((rowb >> 1) & 3)) * 8);
    }

    f32x4 acc[4][4] = {};
    for (int kk = 0; kk < K; kk += 32) {
        __syncthreads();
        gload_lds16(sA1, dA1); gload_lds16(sA2, dA2);
        gload_lds16(sB1, dB1); gload_lds16(sB2, dB2);
        sA1 += 32; sA2 += 32; sB1 += 32; sB2 += 32;
        __syncthreads();
        bf16x8 af[4], bfr[4];
        for (int i = 0; i < 4; ++i) af[i] = *(bf16x8*)&lds_a[offA[i]];
        for (int j = 0; j < 4; ++j) bfr[j] = *(bf16x8*)&lds_b[offB[j]];
        for (int i = 0; i < 4; ++i)
            for (int j = 0; j < 4; ++j)
                acc[i][j] = __builtin_amdgcn_mfma_f32_16x16x32_bf16(af[i], bfr[j], acc[i][j], 0, 0, 0);
    }

    for (int i = 0; i < 4; ++i)
        for (int j = 0; j < 4; ++j)
            for (int r = 0; r < 4; ++r) {
                int m = m0 + wr * 64 + i * 16 + lg * 4 + r;
                int n = n0 + wc * 64 + j * 16 + l15;
                float v = acc[i][j][r];
                if (F32OUT) ((float*)Cv)[(size_t)m * N + n] = v;
                else        ((bf16_t*)Cv)[(size_t)m * N + n] = (bf16_t)v;
            }
}

// ---------------- RoPE (in-place on fused QKV buffer) ----------------
__global__ __launch_bounds__(256) void rope_kernel(bf16_t* __restrict__ QKV,
                                                   const float* __restrict__ cosb,
                                                   const float* __restrict__ sinb) {
    int tid = blockIdx.x * blockDim.x + threadIdx.x;
    int d = tid & 63;
    int h40 = (tid >> 6) % (NH + NKV);
    int bs = tid / (64 * (NH + NKV));
    int col = (h40 < NH) ? h40 * HD : HID + (h40 - NH) * HD;
    bf16_t* rowp = QKV + (size_t)bs * QKV_N + col;
    float x1 = (float)rowp[d];
    float x2 = (float)rowp[d + 64];
    float c1 = cosb[(size_t)bs * HD + d];
    float s1 = sinb[(size_t)bs * HD + d];
    float c2 = cosb[(size_t)bs * HD + d + 64];
    float s2 = sinb[(size_t)bs * HD + d + 64];
    rowp[d]      = (bf16_t)(x1 * c1 - x2 * s1);
    rowp[d + 64] = (bf16_t)(x2 * c2 + x1 * s2);
}

// ---------------- Flash attention: QB=64 (4 waves), KB=64, paired q-tiles ----------------
// Swapped QK^T: S = mfma(K, Q) -> lane holds S[k = k0+nt*16+lg*4+r][q = q0+w*16+l15].
// Reg-staged K/V (loads for step st+1 issued right after the barrier of step st).
#define PITCH_P 72

__global__ __launch_bounds__(256, 3) void attn_fwd(const bf16_t* __restrict__ QKV,
                                                   bf16_t* __restrict__ O) {
    __shared__ __align__(16) bf16_t Kl[64 * 128];      // [k][d], chunk^=(k&7) swizzle (16KB)
    __shared__ __align__(16) bf16_t Vt[128 * 64];      // [d][k], chunk^=(d&7) swizzle (16KB)
    __shared__ __align__(16) bf16_t Pl[4][16 * PITCH_P]; // per-wave P [q][k] (9KB)
    const int tid = threadIdx.x;
    const int lane = tid & 63;
    const int w = tid >> 6;
    const int l15 = lane & 15, lg = lane >> 4;
    const int pr = blockIdx.x, h = blockIdx.y, b = blockIdx.z;
    const int kvh = h >> 2;
    const float scale = 0.08838834764831845f;  // 1/sqrt(128)

    // K staging geometry: chunk q=jj*256+tid -> row=q>>4 (k), ch=q&15 (d-chunk)
    int krow[4], kch[4];
    for (int jj = 0; jj < 4; ++jj) { int q = jj * 256 + tid; krow[jj] = q >> 4; kch[jj] = q & 15; }
    // V transpose staging: thread owns 4(k) x 8(d)
    const int d0 = (tid >> 4) * 8;
    const int k0v = (tid & 15) * 4;
    const int vci = k0v >> 3;     // 16B chunk index 0..7
    const int vsub = k0v & 7;     // 0 or 4 (elem offset inside chunk)

    const bf16_t* Kb0 = QKV + (size_t)(b * S_LEN) * QKV_N + HID + kvh * HD;
    const bf16_t* Vb0 = QKV + (size_t)(b * S_LEN) * QKV_N + HID + NKV * HD + kvh * HD;
    bf16_t* Plw = Pl[w];

    for (int t = 0; t < 2; ++t) {
        const int qt = (t == 0) ? pr : (31 - pr);   // paired tiles: (pr, 31-pr) -> 33 steps/block
        const int q0 = qt * 64;
        const int qrow = q0 + w * 16 + l15;         // q-row this lane HOLDS scores for (softmax)

        bf16x8 qf[4];
        {
            const bf16_t* qp = QKV + (size_t)(b * S_LEN + qrow) * QKV_N + h * HD;
            for (int c = 0; c < 4; ++c) qf[c] = *(const bf16x8*)&qp[c * 32 + lg * 8];
        }

        f32x4 acc_o[8] = {};
        float mrow = -INFF, lrow = 0.f;
        const int nsteps = qt + 1;

        bf16x8 kst[4], vst[4];
        for (int jj = 0; jj < 4; ++jj)
            kst[jj] = *(const bf16x8*)&Kb0[(size_t)krow[jj] * QKV_N + kch[jj] * 8];
        for (int j2 = 0; j2 < 4; ++j2)
            vst[j2] = *(const bf16x8*)&Vb0[(size_t)(k0v + j2) * QKV_N + d0];

        for (int st = 0; st < nsteps; ++st) {
            const int k0 = st * 64;
            __syncthreads();  // everyone done reading prev Kl/Vt
            for (int jj = 0; jj < 4; ++jj)
                *(bf16x8*)&Kl[krow[jj] * 128 + ((kch[jj] ^ (krow[jj] & 7)) * 8)] = kst[jj];
            #pragma unroll
            for (int j = 0; j < 8; ++j) {
                bf16x4 cvec = { vst[0][j], vst[1][j], vst[2][j], vst[3][j] };
                *(bf16x4*)&Vt[(d0 + j) * 64 + ((vci ^ j) << 3) + vsub] = cvec;
            }
            __syncthreads();  // Kl/Vt ready
            if (st + 1 < nsteps) {  // prefetch next tile into regs; hides under compute below
                const bf16_t* Kb = Kb0 + (size_t)(k0 + 64) * QKV_N;
                const bf16_t* Vb = Vb0 + (size_t)(k0 + 64) * QKV_N;
                for (int jj = 0; jj < 4; ++jj)
                    kst[jj] = *(const bf16x8*)&Kb[(size_t)krow[jj] * QKV_N + kch[jj] * 8];
                for (int j2 = 0; j2 < 4; ++j2)
                    vst[j2] = *(const bf16x8*)&Vb[(size_t)(k0v + j2) * QKV_N + d0];
            }
            // QK^T swapped: s[nt] = K(16k) x Q(16q), lane: k=nt*16+lg*4+r (rows), q=l15 (col)
            f32x4 s[4];
            #pragma unroll
            for (int nt = 0; nt < 4; ++nt) {
                s[nt] = (f32x4){0.f, 0.f, 0.f, 0.f};
                const int row = nt * 16 + l15;
                const int rb = row * 128, key = row & 7;
                #pragma unroll
                for (int c = 0; c < 4; ++c) {
                    bf16x8 kf = *(const bf16x8*)&Kl[rb + (((c * 4 + lg) ^ key) * 8)];
                    s[nt] = __builtin_amdgcn_mfma_f32_16x16x32_bf16(kf, qf[c], s[nt], 0, 0, 0);
                }
            }
            // softmax: this lane holds 16 scores for q=qrow; reduce in-reg + 2 shuffles
            float ev[4][4];
            float mx = -INFF;
            #pragma unroll
            for (int nt = 0; nt < 4; ++nt)
                #pragma unroll
                for (int r = 0; r < 4; ++r) {
                    int k = k0 + nt * 16 + lg * 4 + r;
                    float v = (k <= qrow) ? s[nt][r] * scale : -INFF;
                    ev[nt][r] = v;
                    mx = fmaxf(mx, v);
                }
            mx = fmaxf(mx, __shfl_xor(mx, 16));
            mx = fmaxf(mx, __shfl_xor(mx, 32));
            const float mn = fmaxf(mrow, mx);
            const float sc = __expf(mrow - mn);
            float rs = 0.f;
            #pragma unroll
            for (int nt = 0; nt < 4; ++nt)
                #pragma unroll
                for (int r = 0; r < 4; ++r) {
                    float e = __expf(ev[nt][r] - mn);
                    ev[nt][r] = e; rs += e;
                }
            rs += __shfl_xor(rs, 16);
            rs += __shfl_xor(rs, 32);
            mrow = mn;
            lrow = lrow * sc + rs;
            // P -> per-wave LDS: row q=l15, k chunk nt*16+lg*4 (+r), b64 packed
            #pragma unroll
            for (int nt = 0; nt < 4; ++nt) {
                bf16x4 pk = {(bf16_t)ev[nt][0], (bf16_t)ev[nt][1], (bf16_t)ev[nt][2], (bf16_t)ev[nt][3]};
                *(bf16x4*)&Plw[l15 * PITCH_P + nt * 16 + lg * 4] = pk;
            }
            // rescale acc (acc lane holds q_local = lg*4+r, d = nt2*16+l15)
            float scb[4];
            #pragma unroll
            for (int r = 0; r < 4; ++r) scb[r] = __shfl(sc, lg * 4 + r);
            #pragma unroll
            for (int nt2 = 0; nt2 < 8; ++nt2)
                #pragma unroll
                for (int r = 0; r < 4; ++r) acc_o[nt2][r] *= scb[r];
            // PV: A=P[q][k] (row l15), B=Vt[d][k] (row nt2*16+l15, swizzled chunks)
            #pragma unroll
            for (int kc = 0; kc < 2; ++kc) {
                bf16x8 pf = *(const bf16x8*)&Plw[l15 * PITCH_P + kc * 32 + lg * 8];
                #pragma unroll
                for (int nt2 = 0; nt2 < 8; ++nt2) {
                    const int drow = nt2 * 16 + l15;
                    bf16x8 vf = *(const bf16x8*)&Vt[drow * 64 + (((kc * 4 + lg) ^ (drow & 7)) << 3)];
                    acc_o[nt2] = __builtin_amdgcn_mfma_f32_16x16x32_bf16(pf, vf, acc_o[nt2], 0, 0, 0);
                }
            }
        }
        // epilogue: lane holds O[q=q0+w*16+lg*4+r][d=nt2*16+l15]
        float lb[4];
        #pragma unroll
        for (int r = 0; r < 4; ++r) lb[r] = __shfl(lrow, lg * 4 + r);
        #pragma unroll
        for (int nt2 = 0; nt2 < 8; ++nt2)
            #pragma unroll
            for (int r = 0; r < 4; ++r) {
                int q = q0 + w * 16 + lg * 4 + r;
                int d = nt2 * 16 + l15;
                O[((size_t)(b * S_LEN + q)) * (NH * HD) + h * HD + d] = (bf16_t)(acc_o[nt2][r] / lb[r]);
            }
    }
}

// ---------------- launch ----------------
extern "C" void kernel_launch(void* const* d_in, const int* in_sizes, int n_in,
                              void* d_out, int out_size, void* d_ws, size_t ws_size,
                              hipStream_t stream) {
    const float* hs   = (const float*)d_in[0];
    const float* cosb = (const float*)d_in[1];
    const float* sinb = (const float*)d_in[2];
    const float* wq   = (const float*)d_in[3];
    const float* wk   = (const float*)d_in[4];
    const float* wv   = (const float*)d_in[5];
    const float* wo   = (const float*)d_in[6];
    float* out = (float*)d_out;

    const size_t NHS = (size_t)B_SZ * S_LEN * HID;
    const size_t NQKVW = (size_t)QKV_N * HID;
    size_t need = (NHS * 3 + NQKVW * 2) * sizeof(bf16_t);
    if (ws_size < need) return;

    bf16_t* p = (bf16_t*)d_ws;
    bf16_t* hsb  = p; p += NHS;
    bf16_t* wqkv = p; p += NQKVW;
    bf16_t* wob  = p; p += NHS;
    bf16_t* QKVb = p; p += NQKVW;
    bf16_t* Ab   = p; p += NHS;

    auto cvt = [&](const float* src, bf16_t* dst, size_t n) {
        int n4 = (int)(n / 4);
        f2b_kernel<<<(n4 + 255) / 256, 256, 0, stream>>>((const float4*)src, (bf16x4*)dst, n4);
    };
    cvt(hs, hsb, NHS);
    cvt(wq, wqkv, NHS);
    cvt(wk, wqkv + (size_t)HID * HID, (size_t)NKV * HD * HID);
    cvt(wv, wqkv + (size_t)(HID + NKV * HD) * HID, (size_t)NKV * HD * HID);
    cvt(wo, wob, NHS);

    const int M = B_SZ * S_LEN;
    gemm_bt<false><<<dim3(QKV_N / 128, M / 128), 256, 0, stream>>>(hsb, wqkv, QKVb, M, QKV_N, HID);

    int rope_threads = B_SZ * S_LEN * (NH + NKV) * 64;
    rope_kernel<<<rope_threads / 256, 256, 0, stream>>>(QKVb, cosb, sinb);

    attn_fwd<<<dim3(16, NH, B_SZ), 256, 0, stream>>>(QKVb, Ab);

    gemm_bt<true><<<dim3(HID / 128, M / 128), 256, 0, stream>>>(Ab, wob, out, M, HID, HID);
}

// Round 4
// 592.145 us; speedup vs baseline: 2.1981x; 1.1850x over previous
//
#include <hip/hip_runtime.h>
#include <stdint.h>

typedef __bf16 bf16_t;
typedef __bf16 bf16x8 __attribute__((ext_vector_type(8)));
typedef __bf16 bf16x4 __attribute__((ext_vector_type(4)));
typedef float f32x4 __attribute__((ext_vector_type(4)));

#define S_LEN 2048
#define NH 32
#define NKV 8
#define HD 128
#define B_SZ 2
#define HID 4096
#define QKV_N 6144
#define INFF __builtin_inff()

// global -> LDS direct copy, 16B per lane. LDS dest must be linear (base+lane*16) per wave.
__device__ __forceinline__ void gload_lds16(const void* g, void* l) {
    __builtin_amdgcn_global_load_lds(
        (const __attribute__((address_space(1))) void*)(uintptr_t)g,
        (__attribute__((address_space(3))) void*)(uint32_t)(uintptr_t)l,
        16, 0, 0);
}

// ---------------- fp32 -> bf16 convert ----------------
__global__ __launch_bounds__(256) void f2b_kernel(const float4* __restrict__ in,
                                                  bf16x4* __restrict__ out, int n4) {
    int i = blockIdx.x * blockDim.x + threadIdx.x;
    if (i >= n4) return;
    float4 v = in[i];
    bf16x4 o = {(bf16_t)v.x, (bf16_t)v.y, (bf16_t)v.z, (bf16_t)v.w};
    out[i] = o;
}

// ---------------- GEMM 256x256 tile, 8-wave, 4-slot ring, counted vmcnt ----------------
// C[M,N] = A[M,K] @ W[N,K]^T.  BK=32, K-tiles staged 3 ahead, 2 phases/tile.
#define SLOT_E 16384   // elems per slot (A 8192 + B 8192)

#define GTILE(T, STAGE, VMW) do {                                                         \
    const int _sb = ((T) & 3) * SLOT_E;                                                   \
    bf16x8 af[8], bfr[2];                                                                 \
    _Pragma("unroll") for (int i = 0; i < 8; ++i)                                         \
        af[i] = *(const bf16x8*)&lds[_sb + offA[i]];                                      \
    bfr[0] = *(const bf16x8*)&lds[_sb + 8192 + offB[0]];                                  \
    bfr[1] = *(const bf16x8*)&lds[_sb + 8192 + offB[1]];                                  \
    if (STAGE) {                                                                          \
        const int _ss = (((T) + 3) & 3) * SLOT_E;                                         \
        gload_lds16(sA0, &lds[_ss + ldsO0]); gload_lds16(sA1, &lds[_ss + ldsO1]);         \
        sA0 += 32; sA1 += 32;                                                             \
    }                                                                                     \
    __builtin_amdgcn_s_barrier();                                                         \
    asm volatile("s_waitcnt lgkmcnt(0)" ::: "memory");                                    \
    __builtin_amdgcn_sched_barrier(0);                                                    \
    __builtin_amdgcn_s_setprio(1);                                                        \
    _Pragma("unroll") for (int i = 0; i < 8; ++i) {                                       \
        acc[i][0] = __builtin_amdgcn_mfma_f32_16x16x32_bf16(af[i], bfr[0], acc[i][0], 0, 0, 0); \
        acc[i][1] = __builtin_amdgcn_mfma_f32_16x16x32_bf16(af[i], bfr[1], acc[i][1], 0, 0, 0); \
    }                                                                                     \
    __builtin_amdgcn_s_setprio(0);                                                        \
    __builtin_amdgcn_s_barrier();                                                         \
    bf16x8 bfs[2];                                                                        \
    bfs[0] = *(const bf16x8*)&lds[_sb + 8192 + offB[2]];                                  \
    bfs[1] = *(const bf16x8*)&lds[_sb + 8192 + offB[3]];                                  \
    if (STAGE) {                                                                          \
        const int _ss = (((T) + 3) & 3) * SLOT_E;                                         \
        gload_lds16(sB0, &lds[_ss + 8192 + ldsO0]); gload_lds16(sB1, &lds[_ss + 8192 + ldsO1]); \
        sB0 += 32; sB1 += 32;                                                             \
    }                                                                                     \
    __builtin_amdgcn_s_barrier();                                                         \
    asm volatile("s_waitcnt lgkmcnt(0)" ::: "memory");                                    \
    __builtin_amdgcn_sched_barrier(0);                                                    \
    __builtin_amdgcn_s_setprio(1);                                                        \
    _Pragma("unroll") for (int i = 0; i < 8; ++i) {                                       \
        acc[i][2] = __builtin_amdgcn_mfma_f32_16x16x32_bf16(af[i], bfs[0], acc[i][2], 0, 0, 0); \
        acc[i][3] = __builtin_amdgcn_mfma_f32_16x16x32_bf16(af[i], bfs[1], acc[i][3], 0, 0, 0); \
    }                                                                                     \
    __builtin_amdgcn_s_setprio(0);                                                        \
    if ((VMW) == 8)      asm volatile("s_waitcnt vmcnt(8)" ::: "memory");                 \
    else if ((VMW) == 4) asm volatile("s_waitcnt vmcnt(4)" ::: "memory");                 \
    else if ((VMW) == 0) asm volatile("s_waitcnt vmcnt(0)" ::: "memory");                 \
    __builtin_amdgcn_s_barrier();                                                         \
} while (0)

template<bool F32OUT>
__global__ __launch_bounds__(512, 2) void gemm256(const bf16_t* __restrict__ A,
                                                  const bf16_t* __restrict__ W,
                                                  void* __restrict__ Cv,
                                                  int M, int N, int K) {
    __shared__ __align__(16) bf16_t lds[4 * SLOT_E];   // 128 KB: 4 slots x (A 16KB + B 16KB)
    const int tid = threadIdx.x;
    const int lane = tid & 63;
    const int w = tid >> 6;
    const int wm = w >> 2, wn = w & 3;
    const int l15 = lane & 15, lg = lane >> 4;

    // XCD-aware block swizzle (gridDim.x % 8 == 0 guaranteed by launch)
    const int nbx = N >> 8;
    const int cpx = gridDim.x >> 3;
    const int bid = blockIdx.x;
    const int bid2 = (bid & 7) * cpx + (bid >> 3);
    const int m0 = (bid2 / nbx) * 256;
    const int n0 = (bid2 % nbx) * 256;

    // staging geometry: chunk c -> row=c>>2, src col chunk (c&3)^((row>>1)&3); LDS linear at c*16B
    const int c0 = tid, c1 = 512 + tid;
    const int rA0 = c0 >> 2, ch0 = (c0 & 3) ^ ((rA0 >> 1) & 3);
    const int rA1 = c1 >> 2, ch1 = (c1 & 3) ^ ((rA1 >> 1) & 3);
    const bf16_t* sA0 = A + (size_t)(m0 + rA0) * K + ch0 * 8;
    const bf16_t* sA1 = A + (size_t)(m0 + rA1) * K + ch1 * 8;
    const bf16_t* sB0 = W + (size_t)(n0 + rA0) * K + ch0 * 8;
    const bf16_t* sB1 = W + (size_t)(n0 + rA1) * K + ch1 * 8;
    const int ldsO0 = c0 * 8, ldsO1 = c1 * 8;

    // ds_read fragment offsets (within slot region), same XOR both-sides swizzle
    int offA[8], offB[4];
    #pragma unroll
    for (int i = 0; i < 8; ++i) {
        int row = wm * 128 + i * 16 + l15;
        offA[i] = row * 32 + ((lg ^ ((row >> 1) & 3)) * 8);
    }
    #pragma unroll
    for (int j = 0; j < 4; ++j) {
        int row = wn * 64 + j * 16 + l15;
        offB[j] = row * 32 + ((lg ^ ((row >> 1) & 3)) * 8);
    }

    // prologue: stage tiles 0,1,2 (A then B per tile; 4 loads/thread/tile)
    #pragma unroll
    for (int tt = 0; tt < 3; ++tt) {
        const int ss = tt * SLOT_E;
        gload_lds16(sA0, &lds[ss + ldsO0]); gload_lds16(sA1, &lds[ss + ldsO1]);
        gload_lds16(sB0, &lds[ss + 8192 + ldsO0]); gload_lds16(sB1, &lds[ss + 8192 + ldsO1]);
        sA0 += 32; sA1 += 32; sB0 += 32; sB1 += 32;
    }
    asm volatile("s_waitcnt vmcnt(8)" ::: "memory");  // tile 0 fully staged
    __builtin_amdgcn_s_barrier();

    f32x4 acc[8][4] = {};
    const int NT = K >> 5;
    int t = 0;
    for (; t < NT - 3; ++t) GTILE(t, true, 8);
    GTILE(NT - 3, false, 4);
    GTILE(NT - 2, false, 0);
    GTILE(NT - 1, false, -1);

    // epilogue
    #pragma unroll
    for (int i = 0; i < 8; ++i)
        #pragma unroll
        for (int jn = 0; jn < 4; ++jn)
            #pragma unroll
            for (int r = 0; r < 4; ++r) {
                int m = m0 + wm * 128 + i * 16 + lg * 4 + r;
                int n = n0 + wn * 64 + jn * 16 + l15;
                float v = acc[i][jn][r];
                if (F32OUT) ((float*)Cv)[(size_t)m * N + n] = v;
                else        ((bf16_t*)Cv)[(size_t)m * N + n] = (bf16_t)v;
            }
}

// ---------------- RoPE (in-place on fused QKV buffer) ----------------
__global__ __launch_bounds__(256) void rope_kernel(bf16_t* __restrict__ QKV,
                                                   const float* __restrict__ cosb,
                                                   const float* __restrict__ sinb) {
    int tid = blockIdx.x * blockDim.x + threadIdx.x;
    int d = tid & 63;
    int h40 = (tid >> 6) % (NH + NKV);
    int bs = tid / (64 * (NH + NKV));
    int col = (h40 < NH) ? h40 * HD : HID + (h40 - NH) * HD;
    bf16_t* rowp = QKV + (size_t)bs * QKV_N + col;
    float x1 = (float)rowp[d];
    float x2 = (float)rowp[d + 64];
    float c1 = cosb[(size_t)bs * HD + d];
    float s1 = sinb[(size_t)bs * HD + d];
    float c2 = cosb[(size_t)bs * HD + d + 64];
    float s2 = sinb[(size_t)bs * HD + d + 64];
    rowp[d]      = (bf16_t)(x1 * c1 - x2 * s1);
    rowp[d + 64] = (bf16_t)(x2 * c2 + x1 * s2);
}

// ---------------- Flash attention: QB=64 (4 waves), KB=64, paired q-tiles ----------------
#define PITCH_P 72

__global__ __launch_bounds__(256, 3) void attn_fwd(const bf16_t* __restrict__ QKV,
                                                   bf16_t* __restrict__ O) {
    __shared__ __align__(16) bf16_t Kl[64 * 128];
    __shared__ __align__(16) bf16_t Vt[128 * 64];
    __shared__ __align__(16) bf16_t Pl[4][16 * PITCH_P];
    const int tid = threadIdx.x;
    const int lane = tid & 63;
    const int w = tid >> 6;
    const int l15 = lane & 15, lg = lane >> 4;
    const int pr = blockIdx.x, h = blockIdx.y, b = blockIdx.z;
    const int kvh = h >> 2;
    const float scale = 0.08838834764831845f;

    int krow[4], kch[4];
    for (int jj = 0; jj < 4; ++jj) { int q = jj * 256 + tid; krow[jj] = q >> 4; kch[jj] = q & 15; }
    const int d0 = (tid >> 4) * 8;
    const int k0v = (tid & 15) * 4;
    const int vci = k0v >> 3;
    const int vsub = k0v & 7;

    const bf16_t* Kb0 = QKV + (size_t)(b * S_LEN) * QKV_N + HID + kvh * HD;
    const bf16_t* Vb0 = QKV + (size_t)(b * S_LEN) * QKV_N + HID + NKV * HD + kvh * HD;
    bf16_t* Plw = Pl[w];

    for (int t = 0; t < 2; ++t) {
        const int qt = (t == 0) ? pr : (31 - pr);
        const int q0 = qt * 64;
        const int qrow = q0 + w * 16 + l15;

        bf16x8 qf[4];
        {
            const bf16_t* qp = QKV + (size_t)(b * S_LEN + qrow) * QKV_N + h * HD;
            for (int c = 0; c < 4; ++c) qf[c] = *(const bf16x8*)&qp[c * 32 + lg * 8];
        }

        f32x4 acc_o[8] = {};
        float mrow = -INFF, lrow = 0.f;
        const int nsteps = qt + 1;

        bf16x8 kst[4], vst[4];
        for (int jj = 0; jj < 4; ++jj)
            kst[jj] = *(const bf16x8*)&Kb0[(size_t)krow[jj] * QKV_N + kch[jj] * 8];
        for (int j2 = 0; j2 < 4; ++j2)
            vst[j2] = *(const bf16x8*)&Vb0[(size_t)(k0v + j2) * QKV_N + d0];

        for (int st = 0; st < nsteps; ++st) {
            const int k0 = st * 64;
            __syncthreads();
            for (int jj = 0; jj < 4; ++jj)
                *(bf16x8*)&Kl[krow[jj] * 128 + ((kch[jj] ^ (krow[jj] & 7)) * 8)] = kst[jj];
            #pragma unroll
            for (int j = 0; j < 8; ++j) {
                bf16x4 cvec = { vst[0][j], vst[1][j], vst[2][j], vst[3][j] };
                *(bf16x4*)&Vt[(d0 + j) * 64 + ((vci ^ j) << 3) + vsub] = cvec;
            }
            __syncthreads();
            if (st + 1 < nsteps) {
                const bf16_t* Kb = Kb0 + (size_t)(k0 + 64) * QKV_N;
                const bf16_t* Vb = Vb0 + (size_t)(k0 + 64) * QKV_N;
                for (int jj = 0; jj < 4; ++jj)
                    kst[jj] = *(const bf16x8*)&Kb[(size_t)krow[jj] * QKV_N + kch[jj] * 8];
                for (int j2 = 0; j2 < 4; ++j2)
                    vst[j2] = *(const bf16x8*)&Vb[(size_t)(k0v + j2) * QKV_N + d0];
            }
            f32x4 s[4];
            #pragma unroll
            for (int nt = 0; nt < 4; ++nt) {
                s[nt] = (f32x4){0.f, 0.f, 0.f, 0.f};
                const int row = nt * 16 + l15;
                const int rb = row * 128, key = row & 7;
                #pragma unroll
                for (int c = 0; c < 4; ++c) {
                    bf16x8 kf = *(const bf16x8*)&Kl[rb + (((c * 4 + lg) ^ key) * 8)];
                    s[nt] = __builtin_amdgcn_mfma_f32_16x16x32_bf16(kf, qf[c], s[nt], 0, 0, 0);
                }
            }
            float ev[4][4];
            float mx = -INFF;
            #pragma unroll
            for (int nt = 0; nt < 4; ++nt)
                #pragma unroll
                for (int r = 0; r < 4; ++r) {
                    int k = k0 + nt * 16 + lg * 4 + r;
                    float v = (k <= qrow) ? s[nt][r] * scale : -INFF;
                    ev[nt][r] = v;
                    mx = fmaxf(mx, v);
                }
            mx = fmaxf(mx, __shfl_xor(mx, 16));
            mx = fmaxf(mx, __shfl_xor(mx, 32));
            const float mn = fmaxf(mrow, mx);
            const float sc = __expf(mrow - mn);
            float rs = 0.f;
            #pragma unroll
            for (int nt = 0; nt < 4; ++nt)
                #pragma unroll
                for (int r = 0; r < 4; ++r) {
                    float e = __expf(ev[nt][r] - mn);
                    ev[nt][r] = e; rs += e;
                }
            rs += __shfl_xor(rs, 16);
            rs += __shfl_xor(rs, 32);
            mrow = mn;
            lrow = lrow * sc + rs;
            #pragma unroll
            for (int nt = 0; nt < 4; ++nt) {
                bf16x4 pk = {(bf16_t)ev[nt][0], (bf16_t)ev[nt][1], (bf16_t)ev[nt][2], (bf16_t)ev[nt][3]};
                *(bf16x4*)&Plw[l15 * PITCH_P + nt * 16 + lg * 4] = pk;
            }
            float scb[4];
            #pragma unroll
            for (int r = 0; r < 4; ++r) scb[r] = __shfl(sc, lg * 4 + r);
            #pragma unroll
            for (int nt2 = 0; nt2 < 8; ++nt2)
                #pragma unroll
                for (int r = 0; r < 4; ++r) acc_o[nt2][r] *= scb[r];
            #pragma unroll
            for (int kc = 0; kc < 2; ++kc) {
                bf16x8 pf = *(const bf16x8*)&Plw[l15 * PITCH_P + kc * 32 + lg * 8];
                #pragma unroll
                for (int nt2 = 0; nt2 < 8; ++nt2) {
                    const int drow = nt2 * 16 + l15;
                    bf16x8 vf = *(const bf16x8*)&Vt[drow * 64 + (((kc * 4 + lg) ^ (drow & 7)) << 3)];
                    acc_o[nt2] = __builtin_amdgcn_mfma_f32_16x16x32_bf16(pf, vf, acc_o[nt2], 0, 0, 0);
                }
            }
        }
        float lb[4];
        #pragma unroll
        for (int r = 0; r < 4; ++r) lb[r] = __shfl(lrow, lg * 4 + r);
        #pragma unroll
        for (int nt2 = 0; nt2 < 8; ++nt2)
            #pragma unroll
            for (int r = 0; r < 4; ++r) {
                int q = q0 + w * 16 + lg * 4 + r;
                int d = nt2 * 16 + l15;
                O[((size_t)(b * S_LEN + q)) * (NH * HD) + h * HD + d] = (bf16_t)(acc_o[nt2][r] / lb[r]);
            }
    }
}

// ---------------- launch ----------------
extern "C" void kernel_launch(void* const* d_in, const int* in_sizes, int n_in,
                              void* d_out, int out_size, void* d_ws, size_t ws_size,
                              hipStream_t stream) {
    const float* hs   = (const float*)d_in[0];
    const float* cosb = (const float*)d_in[1];
    const float* sinb = (const float*)d_in[2];
    const float* wq   = (const float*)d_in[3];
    const float* wk   = (const float*)d_in[4];
    const float* wv   = (const float*)d_in[5];
    const float* wo   = (const float*)d_in[6];
    float* out = (float*)d_out;

    const size_t NHS = (size_t)B_SZ * S_LEN * HID;
    const size_t NQKVW = (size_t)QKV_N * HID;
    size_t need = (NHS * 3 + NQKVW * 2) * sizeof(bf16_t);
    if (ws_size < need) return;

    bf16_t* p = (bf16_t*)d_ws;
    bf16_t* hsb  = p; p += NHS;
    bf16_t* wqkv = p; p += NQKVW;
    bf16_t* wob  = p; p += NHS;
    bf16_t* QKVb = p; p += NQKVW;
    bf16_t* Ab   = p; p += NHS;

    auto cvt = [&](const float* src, bf16_t* dst, size_t n) {
        int n4 = (int)(n / 4);
        f2b_kernel<<<(n4 + 255) / 256, 256, 0, stream>>>((const float4*)src, (bf16x4*)dst, n4);
    };
    cvt(hs, hsb, NHS);
    cvt(wq, wqkv, NHS);
    cvt(wk, wqkv + (size_t)HID * HID, (size_t)NKV * HD * HID);
    cvt(wv, wqkv + (size_t)(HID + NKV * HD) * HID, (size_t)NKV * HD * HID);
    cvt(wo, wob, NHS);

    const int M = B_SZ * S_LEN;  // 4096
    // QKV: 16 x 24 = 384 blocks; WO: 16 x 16 = 256 blocks (both % 8 == 0)
    gemm256<false><<<(M / 256) * (QKV_N / 256), 512, 0, stream>>>(hsb, wqkv, QKVb, M, QKV_N, HID);

    int rope_threads = B_SZ * S_LEN * (NH + NKV) * 64;
    rope_kernel<<<rope_threads / 256, 256, 0, stream>>>(QKVb, cosb, sinb);

    attn_fwd<<<dim3(16, NH, B_SZ), 256, 0, stream>>>(QKVb, Ab);

    gemm256<true><<<(M / 256) * (HID / 256), 512, 0, stream>>>(Ab, wob, out, M, HID, HID);
}